// Round 1
// baseline (2265.149 us; speedup 1.0000x reference)
//
#include <hip/hip_runtime.h>
#include <hip/hip_bf16.h>

constexpr int NQ = 10000, NV = 19560, CAMS = 6, EMBED = 256, HEADS = 8,
              HEAD_DIM = 32, LEVELS = 4, POINTS = 8;

// ---------------- q = query + query_pos (vectorized) ----------------
__global__ void add_kernel(const float* __restrict__ a, const float* __restrict__ b,
                           float* __restrict__ out, int n4) {
  int i = blockIdx.x * blockDim.x + threadIdx.x;
  if (i < n4) {
    float4 x = ((const float4*)a)[i];
    float4 y = ((const float4*)b)[i];
    float4 z = {x.x + y.x, x.y + y.y, x.z + y.z, x.w + y.w};
    ((float4*)out)[i] = z;
  }
}

// ---------------- per-(cam,q) mask + 1/count ----------------
__global__ void mask_kernel(const int* __restrict__ bev, unsigned char* __restrict__ m,
                            float* __restrict__ cinv) {
  int q = blockIdx.x * blockDim.x + threadIdx.x;
  if (q >= NQ) return;
  int cnt = 0;
  for (int c = 0; c < CAMS; ++c) {
    int any = 0;
    for (int z = 0; z < 4; ++z) any |= bev[((size_t)c * NQ + q) * 4 + z];
    m[c * NQ + q] = (unsigned char)(any != 0);
    cnt += (any != 0);
  }
  cinv[q] = 1.0f / (float)(cnt > 0 ? cnt : 1);
}

// ---------------- fp32 tiled GEMM: C = A(M,K)@B(K,N) + bias(N) [+ add(M,N)] ----------------
// requires N % 64 == 0, K % 16 == 0
__global__ __launch_bounds__(256) void gemm_f32(
    const float* __restrict__ A, const float* __restrict__ B,
    const float* __restrict__ bias, const float* __restrict__ add,
    float* __restrict__ C, int M, int N, int K) {
  __shared__ float As[64][20];   // [m][k], pad to dodge conflicts
  __shared__ float Bs[16][68];   // [k][n]
  const int tid = threadIdx.x;
  const int tc = tid & 15, tr = tid >> 4;
  const int row0 = blockIdx.y * 64, col0 = blockIdx.x * 64;
  const int ar = tid >> 2, ac = (tid & 3) * 4;
  const int br = tid >> 4, bc = (tid & 15) * 4;
  float acc[4][4] = {};
  for (int k0 = 0; k0 < K; k0 += 16) {
    float4 av = {0.f, 0.f, 0.f, 0.f};
    if (row0 + ar < M) av = *(const float4*)&A[(size_t)(row0 + ar) * K + k0 + ac];
    *(float4*)&As[ar][ac] = av;
    float4 bvv = *(const float4*)&B[(size_t)(k0 + br) * N + col0 + bc];
    *(float4*)&Bs[br][bc] = bvv;
    __syncthreads();
#pragma unroll
    for (int kk = 0; kk < 16; ++kk) {
      float a[4], b[4];
#pragma unroll
      for (int i = 0; i < 4; ++i) a[i] = As[tr * 4 + i][kk];
#pragma unroll
      for (int j = 0; j < 4; ++j) b[j] = Bs[kk][tc * 4 + j];
#pragma unroll
      for (int i = 0; i < 4; ++i)
#pragma unroll
        for (int j = 0; j < 4; ++j) acc[i][j] += a[i] * b[j];
    }
    __syncthreads();
  }
#pragma unroll
  for (int i = 0; i < 4; ++i) {
    int row = row0 + tr * 4 + i;
    if (row >= M) continue;
    int col = col0 + tc * 4;
    float4 r;
    r.x = acc[i][0] + bias[col + 0];
    r.y = acc[i][1] + bias[col + 1];
    r.z = acc[i][2] + bias[col + 2];
    r.w = acc[i][3] + bias[col + 3];
    if (add) {
      float4 ad = *(const float4*)&add[(size_t)row * N + col];
      r.x += ad.x; r.y += ad.y; r.z += ad.z; r.w += ad.w;
    }
    *(float4*)&C[(size_t)row * N + col] = r;
  }
}

// ---------------- softmax over 32 (per q,head), in-place ----------------
__global__ void softmax_kernel(float* __restrict__ att) {
  int r = blockIdx.x * blockDim.x + threadIdx.x;
  if (r >= NQ * HEADS) return;
  float* p = att + (size_t)r * 32;
  float mx = -1e30f;
#pragma unroll
  for (int i = 0; i < 32; ++i) mx = fmaxf(mx, p[i]);
  float e[32], sm = 0.f;
#pragma unroll
  for (int i = 0; i < 32; ++i) { e[i] = expf(p[i] - mx); sm += e[i]; }
  float inv = 1.0f / sm;
#pragma unroll
  for (int i = 0; i < 32; ++i) p[i] = e[i] * inv;
}

// ---------------- deformable sampling + masked cam-sum + /count ----------------
// one block per query; thread t -> head = t>>5, dim d = t&31 (coalesced 128B gathers)
__global__ __launch_bounds__(256) void sample_kernel(
    const float* __restrict__ vproj, const float* __restrict__ offr,
    const float* __restrict__ attw, const float* __restrict__ ref,
    const unsigned char* __restrict__ m, const float* __restrict__ cinv,
    float* __restrict__ slots) {
  constexpr int Hs[4] = {92, 46, 23, 12};
  constexpr int Ws[4] = {160, 80, 40, 20};
  constexpr int LSI[4] = {0, 14720, 18400, 19320};
  const int q = blockIdx.x;
  const int t = threadIdx.x;
  const int h = t >> 5, d = t & 31;
  float acc = 0.f;
  for (int c = 0; c < CAMS; ++c) {
    if (!m[c * NQ + q]) continue;
    const float* refc = ref + ((size_t)c * NQ + q) * 8;  // (z=4, xy=2)
    const float* vc = vproj + (size_t)c * NV * EMBED + h * HEAD_DIM + d;
#pragma unroll
    for (int l = 0; l < LEVELS; ++l) {
      const int W = Ws[l], H = Hs[l];
      const float* vl = vc + (size_t)LSI[l] * EMBED;
#pragma unroll
      for (int p = 0; p < POINTS; ++p) {
        const int z = p & 3;
        float rx = refc[z * 2 + 0], ry = refc[z * 2 + 1];
        float ox = offr[(size_t)q * 512 + h * 64 + l * 16 + p * 2 + 0];
        float oy = offr[(size_t)q * 512 + h * 64 + l * 16 + p * 2 + 1];
        float x = rx * (float)W + ox - 0.5f;
        float y = ry * (float)H + oy - 0.5f;
        float x0f = floorf(x), y0f = floorf(y);
        float lx = x - x0f, ly = y - y0f;
        int x0 = (int)x0f, y0 = (int)y0f;
        float a = attw[((size_t)q * HEADS + h) * 32 + l * POINTS + p];
        float s = 0.f;
        bool vx0 = (x0 >= 0) && (x0 < W);
        bool vx1 = (x0 + 1 >= 0) && (x0 + 1 < W);
        if (y0 >= 0 && y0 < H) {
          const float* rp = vl + (size_t)y0 * W * EMBED;
          if (vx0) s += (1.f - lx) * (1.f - ly) * rp[(size_t)x0 * EMBED];
          if (vx1) s += lx * (1.f - ly) * rp[(size_t)(x0 + 1) * EMBED];
        }
        if (y0 + 1 >= 0 && y0 + 1 < H) {
          const float* rp = vl + (size_t)(y0 + 1) * W * EMBED;
          if (vx0) s += (1.f - lx) * ly * rp[(size_t)x0 * EMBED];
          if (vx1) s += lx * ly * rp[(size_t)(x0 + 1) * EMBED];
        }
        acc += a * s;
      }
    }
  }
  slots[(size_t)q * EMBED + t] = acc * cinv[q];
}

extern "C" void kernel_launch(void* const* d_in, const int* in_sizes, int n_in,
                              void* d_out, int out_size, void* d_ws, size_t ws_size,
                              hipStream_t stream) {
  const float* query     = (const float*)d_in[0];
  const float* query_pos = (const float*)d_in[1];
  const float* value     = (const float*)d_in[2];   // (6,19560,1,256) contiguous
  const float* refpts    = (const float*)d_in[3];   // (6,1,10000,4,2)
  const int*   bev       = (const int*)d_in[4];     // (6,1,10000,4) as int32
  const float* Wv   = (const float*)d_in[7];
  const float* bv   = (const float*)d_in[8];
  const float* Woff = (const float*)d_in[9];
  const float* boff = (const float*)d_in[10];
  const float* Watt = (const float*)d_in[11];
  const float* batt = (const float*)d_in[12];
  const float* Wout = (const float*)d_in[13];
  const float* bout = (const float*)d_in[14];
  float* out = (float*)d_out;

  char* ws = (char*)d_ws;
  auto alloc = [&](size_t bytes) {
    char* p = ws;
    ws += (bytes + 255) & ~(size_t)255;
    return p;
  };
  float* q     = (float*)alloc((size_t)NQ * EMBED * 4);
  float* offr  = (float*)alloc((size_t)NQ * 512 * 4);
  float* attw  = (float*)alloc((size_t)NQ * 256 * 4);
  float* vproj = (float*)alloc((size_t)CAMS * NV * EMBED * 4);
  float* slots = (float*)alloc((size_t)NQ * EMBED * 4);
  float* cinv  = (float*)alloc((size_t)NQ * 4);
  unsigned char* msk = (unsigned char*)alloc((size_t)CAMS * NQ);

  int n4 = NQ * EMBED / 4;
  add_kernel<<<(n4 + 255) / 256, 256, 0, stream>>>(query, query_pos, q, n4);
  mask_kernel<<<(NQ + 255) / 256, 256, 0, stream>>>(bev, msk, cinv);

  dim3 gOff(512 / 64, (NQ + 63) / 64);
  gemm_f32<<<gOff, 256, 0, stream>>>(q, Woff, boff, nullptr, offr, NQ, 512, 256);
  dim3 gAtt(256 / 64, (NQ + 63) / 64);
  gemm_f32<<<gAtt, 256, 0, stream>>>(q, Watt, batt, nullptr, attw, NQ, 256, 256);
  softmax_kernel<<<(NQ * HEADS + 255) / 256, 256, 0, stream>>>(attw);

  dim3 gV(256 / 64, (CAMS * NV + 63) / 64);
  gemm_f32<<<gV, 256, 0, stream>>>(value, Wv, bv, nullptr, vproj, CAMS * NV, 256, 256);

  sample_kernel<<<NQ, 256, 0, stream>>>(vproj, offr, attw, refpts, msk, cinv, slots);

  gemm_f32<<<gAtt, 256, 0, stream>>>(slots, Wout, bout, query, out, NQ, 256, 256);
}

// Round 2
// 683.875 us; speedup vs baseline: 3.3122x; 3.3122x over previous
//
#include <hip/hip_runtime.h>
#include <hip/hip_bf16.h>

constexpr int NQ = 10000, NV = 19560, CAMS = 6, EMBED = 256, HEADS = 8,
              HEAD_DIM = 32, LEVELS = 4, POINTS = 8;

typedef unsigned int u32;
typedef unsigned short u16;

__device__ inline float lo_f(u32 v) { union { u32 i; float f; } x; x.i = v << 16; return x.f; }
__device__ inline float hi_f(u32 v) { union { u32 i; float f; } x; x.i = v & 0xffff0000u; return x.f; }
__device__ inline u16 f2bf(float f) {
  __hip_bfloat16 b = __float2bfloat16(f);
  return *(u16*)&b;
}

// ---------------- q = query + query_pos ----------------
__global__ void add_kernel(const float* __restrict__ a, const float* __restrict__ b,
                           float* __restrict__ out, int n4) {
  int i = blockIdx.x * blockDim.x + threadIdx.x;
  if (i < n4) {
    float4 x = ((const float4*)a)[i];
    float4 y = ((const float4*)b)[i];
    float4 z = {x.x + y.x, x.y + y.y, x.z + y.z, x.w + y.w};
    ((float4*)out)[i] = z;
  }
}

// ---------------- per-(cam,q) mask + 1/count ----------------
__global__ void mask_kernel(const int* __restrict__ bev, unsigned char* __restrict__ m,
                            float* __restrict__ cinv) {
  int q = blockIdx.x * blockDim.x + threadIdx.x;
  if (q >= NQ) return;
  int cnt = 0;
  for (int c = 0; c < CAMS; ++c) {
    int any = 0;
    for (int z = 0; z < 4; ++z) any |= bev[((size_t)c * NQ + q) * 4 + z];
    m[c * NQ + q] = (unsigned char)(any != 0);
    cnt += (any != 0);
  }
  cinv[q] = 1.0f / (float)(cnt > 0 ? cnt : 1);
}

// ---------------- fp32 tiled GEMM: C = A(M,K)@B(K,N) + bias(N) [+ add(M,N)] ----------------
__global__ __launch_bounds__(256) void gemm_f32(
    const float* __restrict__ A, const float* __restrict__ B,
    const float* __restrict__ bias, const float* __restrict__ add,
    float* __restrict__ C, int M, int N, int K) {
  __shared__ float As[64][20];
  __shared__ float Bs[16][68];
  const int tid = threadIdx.x;
  const int tc = tid & 15, tr = tid >> 4;
  const int row0 = blockIdx.y * 64, col0 = blockIdx.x * 64;
  const int ar = tid >> 2, ac = (tid & 3) * 4;
  const int br = tid >> 4, bc = (tid & 15) * 4;
  float acc[4][4] = {};
  for (int k0 = 0; k0 < K; k0 += 16) {
    float4 av = {0.f, 0.f, 0.f, 0.f};
    if (row0 + ar < M) av = *(const float4*)&A[(size_t)(row0 + ar) * K + k0 + ac];
    *(float4*)&As[ar][ac] = av;
    float4 bvv = *(const float4*)&B[(size_t)(k0 + br) * N + col0 + bc];
    *(float4*)&Bs[br][bc] = bvv;
    __syncthreads();
#pragma unroll
    for (int kk = 0; kk < 16; ++kk) {
      float a[4], b[4];
#pragma unroll
      for (int i = 0; i < 4; ++i) a[i] = As[tr * 4 + i][kk];
#pragma unroll
      for (int j = 0; j < 4; ++j) b[j] = Bs[kk][tc * 4 + j];
#pragma unroll
      for (int i = 0; i < 4; ++i)
#pragma unroll
        for (int j = 0; j < 4; ++j) acc[i][j] += a[i] * b[j];
    }
    __syncthreads();
  }
#pragma unroll
  for (int i = 0; i < 4; ++i) {
    int row = row0 + tr * 4 + i;
    if (row >= M) continue;
    int col = col0 + tc * 4;
    float4 r;
    r.x = acc[i][0] + bias[col + 0];
    r.y = acc[i][1] + bias[col + 1];
    r.z = acc[i][2] + bias[col + 2];
    r.w = acc[i][3] + bias[col + 3];
    if (add) {
      float4 ad = *(const float4*)&add[(size_t)row * N + col];
      r.x += ad.x; r.y += ad.y; r.z += ad.z; r.w += ad.w;
    }
    *(float4*)&C[(size_t)row * N + col] = r;
  }
}

// ------- Wv GEMM with fused bf16 head-major epilogue: out (cam, head, px, 32) -------
__global__ __launch_bounds__(256) void gemm_wv(
    const float* __restrict__ A, const float* __restrict__ B,
    const float* __restrict__ bias, u16* __restrict__ C, int M) {
  constexpr int N = 256, K = 256;
  __shared__ float As[64][20];
  __shared__ float Bs[16][68];
  const int tid = threadIdx.x;
  const int tc = tid & 15, tr = tid >> 4;
  const int row0 = blockIdx.y * 64, col0 = blockIdx.x * 64;
  const int ar = tid >> 2, ac = (tid & 3) * 4;
  const int br = tid >> 4, bc = (tid & 15) * 4;
  float acc[4][4] = {};
  for (int k0 = 0; k0 < K; k0 += 16) {
    float4 av = {0.f, 0.f, 0.f, 0.f};
    if (row0 + ar < M) av = *(const float4*)&A[(size_t)(row0 + ar) * K + k0 + ac];
    *(float4*)&As[ar][ac] = av;
    float4 bvv = *(const float4*)&B[(size_t)(k0 + br) * N + col0 + bc];
    *(float4*)&Bs[br][bc] = bvv;
    __syncthreads();
#pragma unroll
    for (int kk = 0; kk < 16; ++kk) {
      float a[4], b[4];
#pragma unroll
      for (int i = 0; i < 4; ++i) a[i] = As[tr * 4 + i][kk];
#pragma unroll
      for (int j = 0; j < 4; ++j) b[j] = Bs[kk][tc * 4 + j];
#pragma unroll
      for (int i = 0; i < 4; ++i)
#pragma unroll
        for (int j = 0; j < 4; ++j) acc[i][j] += a[i] * b[j];
    }
    __syncthreads();
  }
#pragma unroll
  for (int i = 0; i < 4; ++i) {
    int row = row0 + tr * 4 + i;
    if (row >= M) continue;
    int cam = row / NV;
    int px = row - cam * NV;
    int col = col0 + tc * 4;
    int h = col >> 5, d = col & 31;
    ushort4 r;
    r.x = f2bf(acc[i][0] + bias[col + 0]);
    r.y = f2bf(acc[i][1] + bias[col + 1]);
    r.z = f2bf(acc[i][2] + bias[col + 2]);
    r.w = f2bf(acc[i][3] + bias[col + 3]);
    *(ushort4*)&C[(((size_t)cam * HEADS + h) * NV + px) * 32 + d] = r;
  }
}

// ---------------- softmax over 32 (per q,head), in-place ----------------
__global__ void softmax_kernel(float* __restrict__ att) {
  int r = blockIdx.x * blockDim.x + threadIdx.x;
  if (r >= NQ * HEADS) return;
  float* p = att + (size_t)r * 32;
  float mx = -1e30f;
#pragma unroll
  for (int i = 0; i < 32; ++i) mx = fmaxf(mx, p[i]);
  float e[32], sm = 0.f;
#pragma unroll
  for (int i = 0; i < 32; ++i) { e[i] = expf(p[i] - mx); sm += e[i]; }
  float inv = 1.0f / sm;
#pragma unroll
  for (int i = 0; i < 32; ++i) p[i] = e[i] * inv;
}

// ---------------- deformable sampling + masked cam-sum + /count ----------------
// wave = 1 query: lane -> head = lane>>3, dim-group dg = lane&7 (4 dims each).
// vproj bf16, layout (cam, head, px, 32): x-corner pairs are adjacent 64B.
__global__ __launch_bounds__(256) void sample_kernel(
    const u16* __restrict__ vproj, const float* __restrict__ offr,
    const float* __restrict__ attw, const float* __restrict__ ref,
    const unsigned char* __restrict__ m, const float* __restrict__ cinv,
    float* __restrict__ slots) {
  constexpr int Hs[4] = {92, 46, 23, 12};
  constexpr int Ws[4] = {160, 80, 40, 20};
  constexpr int LSI[4] = {0, 14720, 18400, 19320};
  const int q = blockIdx.x * 4 + (threadIdx.x >> 6);
  const int lane = threadIdx.x & 63;
  const int h = lane >> 3;
  const int dg4 = (lane & 7) * 4;  // element offset of this lane's 4 dims
  float a0 = 0.f, a1 = 0.f, a2 = 0.f, a3 = 0.f;
  const float* offq = offr + (size_t)q * 512 + h * 64;
  const float* attq = attw + ((size_t)q * HEADS + h) * 32;
  for (int c = 0; c < CAMS; ++c) {
    if (!m[c * NQ + q]) continue;
    const float* refc = ref + ((size_t)c * NQ + q) * 8;
    float rfx[4], rfy[4];
#pragma unroll
    for (int z = 0; z < 4; ++z) { rfx[z] = refc[z * 2]; rfy[z] = refc[z * 2 + 1]; }
    const u16* vch = vproj + ((size_t)c * HEADS + h) * NV * 32;
#pragma unroll
    for (int l = 0; l < LEVELS; ++l) {
      const int W = Ws[l], H = Hs[l];
      const u16* vl = vch + (size_t)LSI[l] * 32;
#pragma unroll
      for (int p = 0; p < POINTS; ++p) {
        const int z = p & 3;
        float2 o = *(const float2*)&offq[l * 16 + p * 2];
        float x = rfx[z] * (float)W + o.x - 0.5f;
        float y = rfy[z] * (float)H + o.y - 0.5f;
        float x0f = floorf(x), y0f = floorf(y);
        float lx = x - x0f, ly = y - y0f;
        int x0 = (int)x0f, y0 = (int)y0f;
        float fx0 = (x0 >= 0 && x0 < W) ? 1.f : 0.f;
        float fx1 = (x0 >= -1 && x0 < W - 1) ? 1.f : 0.f;
        float fy0 = (y0 >= 0 && y0 < H) ? 1.f : 0.f;
        float fy1 = (y0 >= -1 && y0 < H - 1) ? 1.f : 0.f;
        int x0c = min(max(x0, 0), W - 1);
        int x1c = min(max(x0 + 1, 0), W - 1);
        int y0c = min(max(y0, 0), H - 1);
        int y1c = min(max(y0 + 1, 0), H - 1);
        // 4 unconditional 8B gathers (branchless, zero-weighted OOB)
        uint2 v00 = *(const uint2*)(vl + ((size_t)(y0c * W + x0c)) * 32 + dg4);
        uint2 v01 = *(const uint2*)(vl + ((size_t)(y0c * W + x1c)) * 32 + dg4);
        uint2 v10 = *(const uint2*)(vl + ((size_t)(y1c * W + x0c)) * 32 + dg4);
        uint2 v11 = *(const uint2*)(vl + ((size_t)(y1c * W + x1c)) * 32 + dg4);
        float w00 = (1.f - lx) * (1.f - ly) * fx0 * fy0;
        float w01 = lx * (1.f - ly) * fx1 * fy0;
        float w10 = (1.f - lx) * ly * fx0 * fy1;
        float w11 = lx * ly * fx1 * fy1;
        float a = attq[l * 8 + p];
        float s0 = w00 * lo_f(v00.x) + w01 * lo_f(v01.x) + w10 * lo_f(v10.x) + w11 * lo_f(v11.x);
        float s1 = w00 * hi_f(v00.x) + w01 * hi_f(v01.x) + w10 * hi_f(v10.x) + w11 * hi_f(v11.x);
        float s2 = w00 * lo_f(v00.y) + w01 * lo_f(v01.y) + w10 * lo_f(v10.y) + w11 * lo_f(v11.y);
        float s3 = w00 * hi_f(v00.y) + w01 * hi_f(v01.y) + w10 * hi_f(v10.y) + w11 * hi_f(v11.y);
        a0 += a * s0; a1 += a * s1; a2 += a * s2; a3 += a * s3;
      }
    }
  }
  float ci = cinv[q];
  float4 r = {a0 * ci, a1 * ci, a2 * ci, a3 * ci};
  *(float4*)&slots[(size_t)q * EMBED + h * 32 + dg4] = r;
}

extern "C" void kernel_launch(void* const* d_in, const int* in_sizes, int n_in,
                              void* d_out, int out_size, void* d_ws, size_t ws_size,
                              hipStream_t stream) {
  const float* query     = (const float*)d_in[0];
  const float* query_pos = (const float*)d_in[1];
  const float* value     = (const float*)d_in[2];
  const float* refpts    = (const float*)d_in[3];
  const int*   bev       = (const int*)d_in[4];
  const float* Wv   = (const float*)d_in[7];
  const float* bv   = (const float*)d_in[8];
  const float* Woff = (const float*)d_in[9];
  const float* boff = (const float*)d_in[10];
  const float* Watt = (const float*)d_in[11];
  const float* batt = (const float*)d_in[12];
  const float* Wout = (const float*)d_in[13];
  const float* bout = (const float*)d_in[14];
  float* out = (float*)d_out;

  char* ws = (char*)d_ws;
  auto alloc = [&](size_t bytes) {
    char* p = ws;
    ws += (bytes + 255) & ~(size_t)255;
    return p;
  };
  float* q     = (float*)alloc((size_t)NQ * EMBED * 4);
  float* offr  = (float*)alloc((size_t)NQ * 512 * 4);
  float* attw  = (float*)alloc((size_t)NQ * 256 * 4);
  u16*   vproj = (u16*)alloc((size_t)CAMS * NV * EMBED * 2);
  float* slots = (float*)alloc((size_t)NQ * EMBED * 4);
  float* cinv  = (float*)alloc((size_t)NQ * 4);
  unsigned char* msk = (unsigned char*)alloc((size_t)CAMS * NQ);

  int n4 = NQ * EMBED / 4;
  add_kernel<<<(n4 + 255) / 256, 256, 0, stream>>>(query, query_pos, q, n4);
  mask_kernel<<<(NQ + 255) / 256, 256, 0, stream>>>(bev, msk, cinv);

  dim3 gOff(512 / 64, (NQ + 63) / 64);
  gemm_f32<<<gOff, 256, 0, stream>>>(q, Woff, boff, nullptr, offr, NQ, 512, 256);
  dim3 gAtt(256 / 64, (NQ + 63) / 64);
  gemm_f32<<<gAtt, 256, 0, stream>>>(q, Watt, batt, nullptr, attw, NQ, 256, 256);
  softmax_kernel<<<(NQ * HEADS + 255) / 256, 256, 0, stream>>>(attw);

  dim3 gV(256 / 64, (CAMS * NV + 63) / 64);
  gemm_wv<<<gV, 256, 0, stream>>>(value, Wv, bv, vproj, CAMS * NV);

  sample_kernel<<<NQ / 4, 256, 0, stream>>>(vproj, offr, attw, refpts, msk, cinv, slots);

  gemm_f32<<<gAtt, 256, 0, stream>>>(slots, Wout, bout, query, out, NQ, 256, 256);
}

// Round 3
// 601.298 us; speedup vs baseline: 3.7671x; 1.1373x over previous
//
#include <hip/hip_runtime.h>
#include <hip/hip_bf16.h>

constexpr int NQ = 10000, NV = 19560, CAMS = 6, EMBED = 256, HEADS = 8,
              HEAD_DIM = 32, LEVELS = 4, POINTS = 8;
constexpr int MQ_PAD = 10112;          // 79 * 128
constexpr int MV_PAD = 117376;         // 917 * 128

typedef unsigned int u32;
typedef unsigned short u16;
typedef __attribute__((ext_vector_type(8))) short short8v;
typedef __attribute__((ext_vector_type(4))) float f32x4;

__device__ inline float lo_f(u32 v) { union { u32 i; float f; } x; x.i = v << 16; return x.f; }
__device__ inline float hi_f(u32 v) { union { u32 i; float f; } x; x.i = v & 0xffff0000u; return x.f; }
__device__ inline u16 f2bf(float f) {
  __hip_bfloat16 b = __float2bfloat16(f);
  return *(u16*)&b;
}

// ---------------- fp32 -> bf16 row-padded convert (optionally fused add) ----------------
// dst (Mpad, 256) bf16; rows >= M zero-filled. Each thread: 8 elements.
__global__ void conv_bf16_kernel(const float* __restrict__ a, const float* __restrict__ b,
                                 u16* __restrict__ dst, int M, int Mpad) {
  int i = blockIdx.x * blockDim.x + threadIdx.x;
  if (i >= Mpad * 32) return;
  int row = i >> 5;
  int col = (i & 31) * 8;
  u16 o[8];
  if (row < M) {
    const float* pa = a + (size_t)row * 256 + col;
#pragma unroll
    for (int j = 0; j < 8; ++j) {
      float v = pa[j];
      if (b) v += b[(size_t)row * 256 + col + j];
      o[j] = f2bf(v);
    }
  } else {
#pragma unroll
    for (int j = 0; j < 8; ++j) o[j] = 0;
  }
  *(short8v*)&dst[(size_t)row * 256 + col] = *(short8v*)o;
}

// ---------------- weight transpose: src (K=256, N) fp32 -> dst (N, 256) bf16 ----------------
__global__ void transpose_w_kernel(const float* __restrict__ src, u16* __restrict__ dst, int N) {
  int g = blockIdx.x * blockDim.x + threadIdx.x;
  if (g >= N * 256) return;
  int n = g >> 8, k = g & 255;
  dst[(size_t)n * 256 + k] = f2bf(src[(size_t)k * N + n]);
}

// ---------------- per-(cam,q) mask + 1/count ----------------
__global__ void mask_kernel(const int* __restrict__ bev, unsigned char* __restrict__ m,
                            float* __restrict__ cinv) {
  int q = blockIdx.x * blockDim.x + threadIdx.x;
  if (q >= NQ) return;
  int cnt = 0;
  for (int c = 0; c < CAMS; ++c) {
    int any = 0;
    for (int z = 0; z < 4; ++z) any |= bev[((size_t)c * NQ + q) * 4 + z];
    m[c * NQ + q] = (unsigned char)(any != 0);
    cnt += (any != 0);
  }
  cinv[q] = 1.0f / (float)(cnt > 0 ? cnt : 1);
}

// ---------------- bf16 MFMA GEMM: C = A(Mpad,256) @ Bt(N,256)^T + bias ----------------
// 128x128 tile, BK=64, 4 waves (2x2 of 64x64), 16x16x32 MFMA, XOR-swizzled LDS.
// mode 0: fp32 out (M,N). mode 1: bf16 head-major vproj out. mode 2: fp32 out + add.
__global__ __launch_bounds__(256) void gemm_mfma(
    const u16* __restrict__ A, const u16* __restrict__ Bt,
    const float* __restrict__ bias, const float* __restrict__ add,
    void* __restrict__ Cout, int M, int N, int mode) {
  constexpr int K = 256, BK = 64;
  __shared__ u16 As[128 * BK];
  __shared__ u16 Bs[128 * BK];
  const int tid = threadIdx.x;
  const int lane = tid & 63, w = tid >> 6;
  const int wr = w >> 1, wc = w & 1;
  const int row0 = blockIdx.y * 128, col0 = blockIdx.x * 128;
  f32x4 acc[4][4] = {};

  for (int k0 = 0; k0 < K; k0 += BK) {
    // stage 128x64 A and B tiles: 4 x 16B per thread each
    short8v areg[4], breg[4];
#pragma unroll
    for (int j = 0; j < 4; ++j) {
      int e = tid + j * 256;
      int r = e >> 3, cb = (e & 7) * 16;
      areg[j] = *(const short8v*)((const char*)A + ((size_t)(row0 + r) * K + k0) * 2 + cb);
      breg[j] = *(const short8v*)((const char*)Bt + ((size_t)(col0 + r) * K + k0) * 2 + cb);
    }
    __syncthreads();  // previous tile fully consumed
#pragma unroll
    for (int j = 0; j < 4; ++j) {
      int e = tid + j * 256;
      int r = e >> 3, cb = (e & 7) * 16;
      int sw = cb ^ ((r & 7) << 4);
      *(short8v*)((char*)As + r * 128 + sw) = areg[j];
      *(short8v*)((char*)Bs + r * 128 + sw) = breg[j];
    }
    __syncthreads();
#pragma unroll
    for (int kk = 0; kk < 2; ++kk) {
      short8v af[4], bf[4];
#pragma unroll
      for (int m = 0; m < 4; ++m) {
        int r = wr * 64 + m * 16 + (lane & 15);
        int cb = kk * 64 + (lane >> 4) * 16;
        af[m] = *(const short8v*)((const char*)As + r * 128 + (cb ^ ((r & 7) << 4)));
      }
#pragma unroll
      for (int n = 0; n < 4; ++n) {
        int r = wc * 64 + n * 16 + (lane & 15);
        int cb = kk * 64 + (lane >> 4) * 16;
        bf[n] = *(const short8v*)((const char*)Bs + r * 128 + (cb ^ ((r & 7) << 4)));
      }
#pragma unroll
      for (int m = 0; m < 4; ++m)
#pragma unroll
        for (int n = 0; n < 4; ++n)
          acc[m][n] = __builtin_amdgcn_mfma_f32_16x16x32_bf16(af[m], bf[n], acc[m][n], 0, 0, 0);
    }
  }

  // epilogue: D lane mapping col=lane&15, row=(lane>>4)*4+r
#pragma unroll
  for (int m = 0; m < 4; ++m) {
    int rowb = row0 + wr * 64 + m * 16 + (lane >> 4) * 4;
#pragma unroll
    for (int r = 0; r < 4; ++r) {
      int rr = rowb + r;
      if (rr >= M) continue;
#pragma unroll
      for (int n = 0; n < 4; ++n) {
        int col = col0 + wc * 64 + n * 16 + (lane & 15);
        float v = acc[m][n][r] + bias[col];
        if (mode == 0) {
          ((float*)Cout)[(size_t)rr * N + col] = v;
        } else if (mode == 1) {
          int cam = rr / NV;
          int px = rr - cam * NV;
          int h = col >> 5, d = col & 31;
          ((u16*)Cout)[(((size_t)cam * HEADS + h) * NV + px) * 32 + d] = f2bf(v);
        } else {
          ((float*)Cout)[(size_t)rr * N + col] = v + add[(size_t)rr * N + col];
        }
      }
    }
  }
}

// ---------------- softmax over 32 (per q,head), in-place ----------------
__global__ void softmax_kernel(float* __restrict__ att) {
  int r = blockIdx.x * blockDim.x + threadIdx.x;
  if (r >= NQ * HEADS) return;
  float* p = att + (size_t)r * 32;
  float mx = -1e30f;
#pragma unroll
  for (int i = 0; i < 32; ++i) mx = fmaxf(mx, p[i]);
  float e[32], sm = 0.f;
#pragma unroll
  for (int i = 0; i < 32; ++i) { e[i] = expf(p[i] - mx); sm += e[i]; }
  float inv = 1.0f / sm;
#pragma unroll
  for (int i = 0; i < 32; ++i) p[i] = e[i] * inv;
}

// ---------------- deformable sampling + masked cam-sum + /count ----------------
__global__ __launch_bounds__(256) void sample_kernel(
    const u16* __restrict__ vproj, const float* __restrict__ offr,
    const float* __restrict__ attw, const float* __restrict__ ref,
    const unsigned char* __restrict__ m, const float* __restrict__ cinv,
    float* __restrict__ slots) {
  constexpr int Hs[4] = {92, 46, 23, 12};
  constexpr int Ws[4] = {160, 80, 40, 20};
  constexpr int LSI[4] = {0, 14720, 18400, 19320};
  const int q = blockIdx.x * 4 + (threadIdx.x >> 6);
  const int lane = threadIdx.x & 63;
  const int h = lane >> 3;
  const int dg4 = (lane & 7) * 4;
  float a0 = 0.f, a1 = 0.f, a2 = 0.f, a3 = 0.f;
  const float* offq = offr + (size_t)q * 512 + h * 64;
  const float* attq = attw + ((size_t)q * HEADS + h) * 32;
  for (int c = 0; c < CAMS; ++c) {
    if (!m[c * NQ + q]) continue;
    const float* refc = ref + ((size_t)c * NQ + q) * 8;
    float rfx[4], rfy[4];
#pragma unroll
    for (int z = 0; z < 4; ++z) { rfx[z] = refc[z * 2]; rfy[z] = refc[z * 2 + 1]; }
    const u16* vch = vproj + ((size_t)c * HEADS + h) * NV * 32;
#pragma unroll
    for (int l = 0; l < LEVELS; ++l) {
      const int W = Ws[l], H = Hs[l];
      const u16* vl = vch + (size_t)LSI[l] * 32;
#pragma unroll
      for (int p = 0; p < POINTS; ++p) {
        const int z = p & 3;
        float2 o = *(const float2*)&offq[l * 16 + p * 2];
        float x = rfx[z] * (float)W + o.x - 0.5f;
        float y = rfy[z] * (float)H + o.y - 0.5f;
        float x0f = floorf(x), y0f = floorf(y);
        float lx = x - x0f, ly = y - y0f;
        int x0 = (int)x0f, y0 = (int)y0f;
        float fx0 = (x0 >= 0 && x0 < W) ? 1.f : 0.f;
        float fx1 = (x0 >= -1 && x0 < W - 1) ? 1.f : 0.f;
        float fy0 = (y0 >= 0 && y0 < H) ? 1.f : 0.f;
        float fy1 = (y0 >= -1 && y0 < H - 1) ? 1.f : 0.f;
        int x0c = min(max(x0, 0), W - 1);
        int x1c = min(max(x0 + 1, 0), W - 1);
        int y0c = min(max(y0, 0), H - 1);
        int y1c = min(max(y0 + 1, 0), H - 1);
        uint2 v00 = *(const uint2*)(vl + ((size_t)(y0c * W + x0c)) * 32 + dg4);
        uint2 v01 = *(const uint2*)(vl + ((size_t)(y0c * W + x1c)) * 32 + dg4);
        uint2 v10 = *(const uint2*)(vl + ((size_t)(y1c * W + x0c)) * 32 + dg4);
        uint2 v11 = *(const uint2*)(vl + ((size_t)(y1c * W + x1c)) * 32 + dg4);
        float w00 = (1.f - lx) * (1.f - ly) * fx0 * fy0;
        float w01 = lx * (1.f - ly) * fx1 * fy0;
        float w10 = (1.f - lx) * ly * fx0 * fy1;
        float w11 = lx * ly * fx1 * fy1;
        float a = attq[l * 8 + p];
        float s0 = w00 * lo_f(v00.x) + w01 * lo_f(v01.x) + w10 * lo_f(v10.x) + w11 * lo_f(v11.x);
        float s1 = w00 * hi_f(v00.x) + w01 * hi_f(v01.x) + w10 * hi_f(v10.x) + w11 * hi_f(v11.x);
        float s2 = w00 * lo_f(v00.y) + w01 * lo_f(v01.y) + w10 * lo_f(v10.y) + w11 * lo_f(v11.y);
        float s3 = w00 * hi_f(v00.y) + w01 * hi_f(v01.y) + w10 * hi_f(v10.y) + w11 * hi_f(v11.y);
        a0 += a * s0; a1 += a * s1; a2 += a * s2; a3 += a * s3;
      }
    }
  }
  float ci = cinv[q];
  float4 r = {a0 * ci, a1 * ci, a2 * ci, a3 * ci};
  *(float4*)&slots[(size_t)q * EMBED + h * 32 + dg4] = r;
}

extern "C" void kernel_launch(void* const* d_in, const int* in_sizes, int n_in,
                              void* d_out, int out_size, void* d_ws, size_t ws_size,
                              hipStream_t stream) {
  const float* query     = (const float*)d_in[0];
  const float* query_pos = (const float*)d_in[1];
  const float* value     = (const float*)d_in[2];
  const float* refpts    = (const float*)d_in[3];
  const int*   bev       = (const int*)d_in[4];
  const float* Wv   = (const float*)d_in[7];
  const float* bv   = (const float*)d_in[8];
  const float* Woff = (const float*)d_in[9];
  const float* boff = (const float*)d_in[10];
  const float* Watt = (const float*)d_in[11];
  const float* batt = (const float*)d_in[12];
  const float* Wout = (const float*)d_in[13];
  const float* bout = (const float*)d_in[14];
  float* out = (float*)d_out;

  char* ws = (char*)d_ws;
  auto alloc = [&](size_t bytes) {
    char* p = ws;
    ws += (bytes + 255) & ~(size_t)255;
    return p;
  };
  u16*   qbf   = (u16*)alloc((size_t)MQ_PAD * 256 * 2);
  u16*   vbf   = (u16*)alloc((size_t)MV_PAD * 256 * 2);
  u16*   sbf   = (u16*)alloc((size_t)MQ_PAD * 256 * 2);
  u16*   WvT   = (u16*)alloc((size_t)256 * 256 * 2);
  u16*   WoffT = (u16*)alloc((size_t)512 * 256 * 2);
  u16*   WattT = (u16*)alloc((size_t)256 * 256 * 2);
  u16*   WoutT = (u16*)alloc((size_t)256 * 256 * 2);
  float* offr  = (float*)alloc((size_t)NQ * 512 * 4);
  float* attw  = (float*)alloc((size_t)NQ * 256 * 4);
  u16*   vproj = (u16*)alloc((size_t)CAMS * NV * EMBED * 2);
  float* slots = (float*)alloc((size_t)NQ * EMBED * 4);
  float* cinv  = (float*)alloc((size_t)NQ * 4);
  unsigned char* msk = (unsigned char*)alloc((size_t)CAMS * NQ);

  // q = query + query_pos -> bf16 (padded)
  conv_bf16_kernel<<<(MQ_PAD * 32 + 255) / 256, 256, 0, stream>>>(query, query_pos, qbf, NQ, MQ_PAD);
  mask_kernel<<<(NQ + 255) / 256, 256, 0, stream>>>(bev, msk, cinv);
  transpose_w_kernel<<<512, 256, 0, stream>>>(Woff, WoffT, 512);
  transpose_w_kernel<<<256, 256, 0, stream>>>(Watt, WattT, 256);
  transpose_w_kernel<<<256, 256, 0, stream>>>(Wv, WvT, 256);
  transpose_w_kernel<<<256, 256, 0, stream>>>(Wout, WoutT, 256);

  dim3 gOff(512 / 128, MQ_PAD / 128);
  gemm_mfma<<<gOff, 256, 0, stream>>>(qbf, WoffT, boff, nullptr, offr, NQ, 512, 0);
  dim3 gAtt(256 / 128, MQ_PAD / 128);
  gemm_mfma<<<gAtt, 256, 0, stream>>>(qbf, WattT, batt, nullptr, attw, NQ, 256, 0);
  softmax_kernel<<<(NQ * HEADS + 255) / 256, 256, 0, stream>>>(attw);

  conv_bf16_kernel<<<(MV_PAD * 32 + 255) / 256, 256, 0, stream>>>(value, nullptr, vbf, CAMS * NV, MV_PAD);
  dim3 gV(256 / 128, MV_PAD / 128);
  gemm_mfma<<<gV, 256, 0, stream>>>(vbf, WvT, bv, nullptr, vproj, CAMS * NV, 256, 1);

  sample_kernel<<<NQ / 4, 256, 0, stream>>>(vproj, offr, attw, refpts, msk, cinv, slots);

  conv_bf16_kernel<<<(MQ_PAD * 32 + 255) / 256, 256, 0, stream>>>(slots, nullptr, sbf, NQ, MQ_PAD);
  gemm_mfma<<<gAtt, 256, 0, stream>>>(sbf, WoutT, bout, query, out, NQ, 256, 2);
}